// Round 12
// baseline (163.010 us; speedup 1.0000x reference)
//
#include <hip/hip_runtime.h>
#include <cstdint>
#include <cstddef>

namespace {

constexpr int B_ = 32, F_ = 64, T_ = 20, N_ = 512, A_ = 64;
constexpr int EINC = 2048, NEDGE = 128, COUT = 128, CIN = 128;
constexpr int THREADS = 1024;
constexpr int NBT = B_ * T_;        // 640 instances
constexpr int GRID_WS = 512;        // persistent blocks (2/CU x 256 CUs)

// ---- LDS layout (word offsets), total 17924 w = 71696 B ----
// 2 blocks/CU (thread-capped). Xq f32 [128][132] overlays everything from
// word 1028 up (dge..ST all dead after P5); srt8+ofn stay below (live thru P6).
// s_nid/s_eid (P0..P3 only) overlay the EQ/ST region. Word 1026 (ofn pad) is
// the work-steal broadcast slot.
constexpr int L_SRT8 = 0;        // u8[2048] = 512 w  (edge ids, node-sorted)
constexpr int L_OFN  = 512;      // 513 int (+3 pad)
constexpr int L_NXT  = 1026;     // 1 int: stolen-instance broadcast (ofn pad)
constexpr int L_XQ   = 1028;     // f32 [128][132] = 16896 w   (overlay region)
constexpr int L_DGE  = 1028;     // 128 int
constexpr int L_CUE  = 1156;     // 128 int
constexpr int L_OFE  = 1284;     // 129 int (+3 pad)
constexpr int L_DGN  = 1416;     // 512 int
constexpr int L_CUN  = 1928;     // 512 int
constexpr int L_ESR  = 2440;     // u16[2048] = 1024 w (node ids, edge-sorted)
constexpr int L_EQ   = 3464;     // 2048 w: K=32 slab, 128 rows x 16 words (bf16 pairs)
constexpr int L_ST   = 5512;     // 8192 w: feat round, 512 nodes x 16 words (bf16 pairs)
constexpr int XQS    = 132;      // Xq row stride (128+4 pad)
constexpr int LDS_WORDS = L_XQ + NEDGE * XQS;   // 17924
constexpr int LDS_BYTES = LDS_WORDS * 4;        // 71696

typedef unsigned u32x8 __attribute__((ext_vector_type(8)));
typedef float f32x4v __attribute__((ext_vector_type(4)));
typedef short bf16x8v __attribute__((ext_vector_type(8)));

__device__ inline unsigned short f2bf(float f) {
    unsigned int u = __float_as_uint(f);
    u = u + 0x7FFFu + ((u >> 16) & 1u);   // RNE
    return (unsigned short)(u >> 16);
}
__device__ inline unsigned packbf(float lo, float hi) {
    return ((unsigned)f2bf(hi) << 16) | (unsigned)f2bf(lo);
}
__device__ inline float bflo(unsigned p) { return __uint_as_float(p << 16); }
__device__ inline float bfhi(unsigned p) { return __uint_as_float(p & 0xFFFF0000u); }

// Load 16-channel chunk CC of node n into 8 bf16-pair words.
// CC<4: x channels (coalesced along n); CC>=4: ssa (float4 x4 per node).
#define LOAD_CHUNK(CC, DST) do {                                              \
    const int c_ = (CC);                                                      \
    if (c_ < 4) {                                                             \
        const float* xr_ = x + (((size_t)b * F_ + c_ * 16) * T_ + t) * N_ + n; \
        _Pragma("unroll")                                                     \
        for (int m_ = 0; m_ < 8; ++m_) {                                      \
            float f0_ = xr_[(size_t)(2 * m_) * (T_ * N_)];                    \
            float f1_ = xr_[(size_t)(2 * m_ + 1) * (T_ * N_)];                \
            DST[m_] = packbf(f0_, f1_);                                       \
        }                                                                     \
    } else {                                                                  \
        const float* sr_ = ssa + ((size_t)bt * N_ + n) * A_ + (c_ - 4) * 16;  \
        _Pragma("unroll")                                                     \
        for (int m_ = 0; m_ < 4; ++m_) {                                      \
            float4 u_ = *(const float4*)(sr_ + 4 * m_);                       \
            DST[2 * m_]     = packbf(u_.x, u_.y);                             \
            DST[2 * m_ + 1] = packbf(u_.z, u_.w);                             \
        }                                                                     \
    }                                                                         \
} while (0)

// Pre-kernel: pack theta f32 -> bf16 pairs in MFMA B-frag order into d_ws,
// and seed the work-steal queue (word 8192) to GRID_WS.
// frag f = ct*4 + kk (ct = col-tile 0..7, kk = K-step/round 0..3); lane l holds
// co = ct*16 + (l&15), ci = kk*32 + (l>>4)*8 + 2*kq (+1), kq = 0..3.
__global__ __launch_bounds__(256)
void theta_pack(const float* __restrict__ theta, unsigned* __restrict__ ws) {
    int w = blockIdx.x * 256 + threadIdx.x;     // 0..8191
    int f = w >> 8, rem = w & 255;
    int l = rem >> 2, kq = rem & 3;
    int kk = f & 3, ct = f >> 2;
    int co = ct * 16 + (l & 15);
    int ci = kk * 32 + (l >> 4) * 8 + kq * 2;
    const float2 tv = *(const float2*)(theta + (size_t)co * CIN + ci);
    ws[w] = packbf(tv.x, tv.y);
    if (w == 0) ws[8192] = (unsigned)GRID_WS;   // queue: next unclaimed instance
}

// 1024 threads, 8 waves/EU -> 2 blocks/CU (32 waves/CU, thread-capped).
// HAS_WS: persistent blocks; each processes its static instance then steals
// more from the global queue. bt is forced into an SGPR via readfirstlane so
// all derived addressing stays scalar (R11's VGPR spill cause).
template<bool HAS_WS>
__global__ __launch_bounds__(THREADS, 8)
void hgconv(const float* __restrict__ x, const int* __restrict__ H,
            const float* __restrict__ ssa, const float* __restrict__ theta,
            const float* __restrict__ bias, float* __restrict__ out,
            const unsigned* __restrict__ thw, unsigned* __restrict__ wq)
{
    extern __shared__ float sf[];
    int* si = (int*)sf;

    const int tid = (int)threadIdx.x;

    unsigned char*  s_srt8  = (unsigned char*)(si + L_SRT8);
    int*            s_ofn   = si + L_OFN;
    int*            s_ofe   = si + L_OFE;
    int*            s_dge   = si + L_DGE;
    int*            s_cue   = si + L_CUE;
    int*            s_dgn   = si + L_DGN;
    int*            s_cun   = si + L_CUN;
    unsigned short* s_esr16 = (unsigned short*)(si + L_ESR);
    unsigned*       s_eq16  = (unsigned*)(si + L_EQ);
    unsigned*       s_st16  = (unsigned*)(si + L_ST);
    int*            s_nid   = si + L_EQ;          // P0..P3 only
    int*            s_eid   = si + L_ST;          // P0..P3 only
    float*          s_xq    = sf + L_XQ;          // after P5

    const int n  = tid & (N_ - 1);   // node (staging / predicates)
    const int hf = tid >> 9;         // which 16-ch half of the 32-ch round

    // instance-invariant lane constants
    const int eg = tid >> 3;         // edge 0..127
    const int ep = tid & 7;          // 4-channel group 0..7
    const int wv = tid >> 6, l = tid & 63;
    const int q  = l >> 4, lco = l & 15;
    const int rt = wv >> 1;          // row-tile 0..7
    const int cth = (wv & 1) * 4;    // col-tile base (0 or 4)
    const int ar = rt * 16 + lco;    // A-frag edge row
    const int aoff = ar * 16 + ((4 * q) ^ ((ar & 3) << 2));   // swizzled quad

    int bt = (int)blockIdx.x;        // static first instance (SGPR)

    for (;;) {
        const int b = bt / T_;
        const int t = bt - b * T_;

        // ---- P0: load incidence, zero degrees ----
        const int* Hb = H + (size_t)bt * (2 * EINC);
        #pragma unroll
        for (int k = 0; k < EINC / THREADS; ++k) {
            int i = tid + k * THREADS;
            s_nid[i] = Hb[i];
            s_eid[i] = Hb[EINC + i];
        }
        if (tid < N_)    s_dgn[tid] = 0;
        if (tid < NEDGE) s_dge[tid] = 0;
        __syncthreads();

        // ---- P1: degrees ----
        #pragma unroll
        for (int k = 0; k < EINC / THREADS; ++k) {
            int i = tid + k * THREADS;
            atomicAdd(&s_dgn[s_nid[i]], 1);
            atomicAdd(&s_dge[s_eid[i]], 1);
        }
        __syncthreads();

        const bool act = s_dgn[n] > 0;
        u32x8 vv;
        if (act) LOAD_CHUNK(hf, vv);     // round-0 halves; hides under scans/sort

        // ---- P2: exclusive scans (wave0: edges, wave1: nodes) ----
        if (tid < 64) {
            const int ll = tid;
            int d0 = s_dge[2 * ll], d1 = s_dge[2 * ll + 1];
            int run = d0 + d1;
            int scan = run;
            #pragma unroll
            for (int d = 1; d < 64; d <<= 1) {
                int o = __shfl_up(scan, d);
                if (ll >= d) scan += o;
            }
            int excl = scan - run;
            s_ofe[2 * ll] = excl;
            s_ofe[2 * ll + 1] = excl + d0;
            if (ll == 63) s_ofe[NEDGE] = scan;
        } else if (tid < 128) {
            const int ll = tid & 63;
            int v, loc[8], run = 0;
            #pragma unroll
            for (int qq = 0; qq < 8; ++qq) { v = s_dgn[ll * 8 + qq]; loc[qq] = run; run += v; }
            int scan = run;
            #pragma unroll
            for (int d = 1; d < 64; d <<= 1) {
                int o = __shfl_up(scan, d);
                if (ll >= d) scan += o;
            }
            int excl = scan - run;
            #pragma unroll
            for (int qq = 0; qq < 8; ++qq) s_ofn[ll * 8 + qq] = excl + loc[qq];
            if (ll == 63) s_ofn[N_] = scan;
        }
        __syncthreads();

        if (tid < N_)    s_cun[tid] = s_ofn[tid];
        if (tid < NEDGE) s_cue[tid] = s_ofe[tid];
        __syncthreads();

        // ---- P3: counting-sort scatter (esr u16 by edge, srt u8 by node) ----
        #pragma unroll
        for (int k = 0; k < EINC / THREADS; ++k) {
            int i = tid + k * THREADS;
            int nd = s_nid[i];
            int e  = s_eid[i];
            int pe = atomicAdd(&s_cue[e], 1);
            s_esr16[pe] = (unsigned short)nd;
            int pn = atomicAdd(&s_cun[nd], 1);
            s_srt8[pn] = (unsigned char)e;
        }
        __syncthreads();                 // s_nid/s_eid DEAD; EQ/ST usable

        // ---- P4+P5 fused: 4 rounds x {stage 32ch, gather->EQ, MFMA K-step} ----
        const int k0 = s_ofe[eg], k1 = s_ofe[eg + 1];
        const float binv = (k1 > k0) ? 1.0f / (float)(k1 - k0) : 0.0f;

        f32x4v acc[4];
        #pragma unroll
        for (int i = 0; i < 4; ++i) acc[i] = (f32x4v){0.f, 0.f, 0.f, 0.f};

        #pragma unroll
        for (int r = 0; r < 4; ++r) {
            if (act) {                   // stage this thread's 8 words (4 uint2, swizzled)
                #pragma unroll
                for (int p2 = 0; p2 < 4; ++p2) {
                    int P = 4 * hf + p2;                       // pair index 0..7
                    unsigned* sp = s_st16 + n * 16 + ((2 * P) ^ ((n & 7) << 1));
                    *(uint2*)sp = make_uint2(vv[2 * p2], vv[2 * p2 + 1]);
                }
            }
            __syncthreads();             // B1: stage visible; prev MFMA EQ-reads done

            if (r < 3 && act) LOAD_CHUNK(2 * r + 2 + hf, vv);  // reload under gather

            {   // gather 4 channels (words 2ep,2ep+1) for edge eg
                float a0 = 0.f, a1 = 0.f, a2 = 0.f, a3 = 0.f;
                for (int k = k0; k < k1; ++k) {
                    int nd = (int)s_esr16[k];
                    uint2 pr = *(const uint2*)(s_st16 + nd * 16
                                    + ((2 * ep) ^ ((nd & 7) << 1)));
                    a0 += bflo(pr.x); a1 += bfhi(pr.x);
                    a2 += bflo(pr.y); a3 += bfhi(pr.y);
                }
                unsigned* qp = s_eq16 + eg * 16 + ((2 * ep) ^ ((eg & 3) << 2));
                *(uint2*)qp = make_uint2(packbf(a0 * binv, a1 * binv),
                                         packbf(a2 * binv, a3 * binv));
            }
            __syncthreads();             // B2: EQ visible; ST reads done

            {   // MFMA K-step r: A = EQ row-tile, B = theta frags
                bf16x8v av = *(const bf16x8v*)(s_eq16 + aoff);
                if (HAS_WS) {
                    #pragma unroll
                    for (int i = 0; i < 4; ++i) {
                        uint4 u = ((const uint4*)thw)[((cth + i) * 4 + r) * 64 + l];
                        acc[i] = __builtin_amdgcn_mfma_f32_16x16x32_bf16(
                            av, *(const bf16x8v*)&u, acc[i], 0, 0, 0);
                    }
                } else {
                    #pragma unroll
                    for (int i = 0; i < 4; ++i) {
                        const float* tp = theta + (size_t)((cth + i) * 16 + lco) * CIN
                                        + r * 32 + q * 8;
                        float4 t0 = *(const float4*)tp;
                        float4 t1 = *(const float4*)(tp + 4);
                        unsigned pw[4] = { packbf(t0.x, t0.y), packbf(t0.z, t0.w),
                                           packbf(t1.x, t1.y), packbf(t1.z, t1.w) };
                        acc[i] = __builtin_amdgcn_mfma_f32_16x16x32_bf16(
                            av, *(const bf16x8v*)pw, acc[i], 0, 0, 0);
                    }
                }
            }
        }
        __syncthreads();                 // B3: all EQ reads done; Xq overlay may begin

        // ---- Xq write: D-frag (col = lco, row = q*4+reg) -> f32 [128][132] ----
        #pragma unroll
        for (int i = 0; i < 4; ++i) {
            const int co = (cth + i) * 16 + lco;
            #pragma unroll
            for (int reg = 0; reg < 4; ++reg)
                s_xq[(rt * 16 + q * 4 + reg) * XQS + co] = acc[i][reg];
        }
        __syncthreads();

        // ---- P6: single pass; per visit one b128; float4 coalesced store ----
        {
            const int lw = tid & 31;
            const int g  = tid >> 5;     // 0..31
            float4 bsv = *(const float4*)(bias + 4 * lw);
            for (int nn = g; nn < N_; nn += 32) {
                int o0 = s_ofn[nn], o1 = s_ofn[nn + 1];
                float f0 = 0.f, f1 = 0.f, f2 = 0.f, f3 = 0.f;
                for (int k = o0; k < o1; ++k) {
                    int e = (int)s_srt8[k];
                    float4 v = *(const float4*)(s_xq + e * XQS + 4 * lw);
                    f0 += v.x; f1 += v.y; f2 += v.z; f3 += v.w;
                }
                float dinv = (o1 > o0) ? 1.0f / (float)(o1 - o0) : 0.0f;
                float* op = out + ((size_t)bt * N_ + nn) * COUT + 4 * lw;
                *(float4*)op = make_float4(f0 * dinv + bsv.x, f1 * dinv + bsv.y,
                                           f2 * dinv + bsv.z, f3 * dinv + bsv.w);
            }
        }

        if (!HAS_WS) break;              // static grid covers all instances

        // ---- steal next instance (bt forced back to SGPR: keeps addressing scalar) ----
        __syncthreads();                 // all P6 LDS reads done before reuse
        if (tid == 0) si[L_NXT] = (int)atomicAdd(wq, 1u);
        __syncthreads();
        bt = __builtin_amdgcn_readfirstlane(si[L_NXT]);
        if (bt >= NBT) break;
    }
}

} // namespace

extern "C" void kernel_launch(void* const* d_in, const int* in_sizes, int n_in,
                              void* d_out, int out_size, void* d_ws, size_t ws_size,
                              hipStream_t stream) {
    const float* x     = (const float*)d_in[0];
    const int*   H     = (const int*)d_in[1];
    const float* ssa   = (const float*)d_in[2];
    // d_in[3] = W, unused by the conv (matches reference)
    const float* theta = (const float*)d_in[4];
    const float* bias  = (const float*)d_in[5];
    float* outp = (float*)d_out;

    const bool use_ws = (d_ws != nullptr) && (ws_size >= 32772);
    if (use_ws) {
        hipLaunchKernelGGL(theta_pack, dim3(32), dim3(256), 0, stream,
                           theta, (unsigned*)d_ws);
        (void)hipFuncSetAttribute((const void*)&hgconv<true>,
                                  hipFuncAttributeMaxDynamicSharedMemorySize, LDS_BYTES);
        hipLaunchKernelGGL(hgconv<true>, dim3(GRID_WS), dim3(THREADS), LDS_BYTES,
                           stream, x, H, ssa, theta, bias, outp,
                           (const unsigned*)d_ws, (unsigned*)d_ws + 8192);
    } else {
        (void)hipFuncSetAttribute((const void*)&hgconv<false>,
                                  hipFuncAttributeMaxDynamicSharedMemorySize, LDS_BYTES);
        hipLaunchKernelGGL(hgconv<false>, dim3(NBT), dim3(THREADS), LDS_BYTES,
                           stream, x, H, ssa, theta, bias, outp, nullptr, nullptr);
    }
}

// Round 13
// 74.720 us; speedup vs baseline: 2.1816x; 2.1816x over previous
//
#include <hip/hip_runtime.h>
#include <cstdint>
#include <cstddef>

namespace {

constexpr int B_ = 32, F_ = 64, T_ = 20, N_ = 512, A_ = 64;
constexpr int EINC = 2048, NEDGE = 128, COUT = 128, CIN = 128;
constexpr int THREADS = 1024;
constexpr int NBT = B_ * T_;     // 640 instances

// ---- LDS layout (word offsets), total 18180 w = 72720 B ----
// 2 blocks/CU (thread-capped; 2x72720 <= 160KB). Xq f32 [128][132] overlays
// words 1028..17924 (dge..ST dead after P5); srt8+ofn live thru P6.
// s_nid/s_eid (P0..P3 only) overlay the EQ/ST region.
constexpr int L_SRT8 = 0;        // u8[2048] = 512 w  (edge ids, node-sorted)
constexpr int L_OFN  = 512;      // 513 int (+3 pad)
constexpr int L_XQ   = 1028;     // f32 [128][132] = 16896 w   (overlay region)
constexpr int L_DGE  = 1028;     // 128 int (valid thru P5: Xq written after B3)
constexpr int L_CUE  = 1156;     // 128 int
constexpr int L_OFE  = 1284;     // 129 int (+3 pad)
constexpr int L_DGN  = 1416;     // 512 int
constexpr int L_CUN  = 1928;     // 512 int
constexpr int L_ESR  = 2440;     // u16[2048] = 1024 w (node ids, edge-sorted)
constexpr int L_EQ   = 3464;     // 2048 w: K=32 slab, 128 rows x 16 words (bf16 pairs)
constexpr int L_ST   = 5512;     // 8192 w: feat round, 512 nodes x 16 words (bf16 pairs)
constexpr int L_HST  = 17924;    // 64 int: edge-degree histogram
constexpr int L_CRS  = 17988;    // 64 int: bucket cursors
constexpr int L_PRM  = 18052;    // 128 int: degree-sorted edge permutation
constexpr int XQS    = 132;      // Xq row stride (128+4 pad)
constexpr int LDS_WORDS = 18180;
constexpr int LDS_BYTES = LDS_WORDS * 4;        // 72720

typedef unsigned u32x8 __attribute__((ext_vector_type(8)));
typedef float f32x4v __attribute__((ext_vector_type(4)));
typedef short bf16x8v __attribute__((ext_vector_type(8)));

__device__ inline unsigned short f2bf(float f) {
    unsigned int u = __float_as_uint(f);
    u = u + 0x7FFFu + ((u >> 16) & 1u);   // RNE
    return (unsigned short)(u >> 16);
}
__device__ inline unsigned packbf(float lo, float hi) {
    return ((unsigned)f2bf(hi) << 16) | (unsigned)f2bf(lo);
}
__device__ inline float bflo(unsigned p) { return __uint_as_float(p << 16); }
__device__ inline float bfhi(unsigned p) { return __uint_as_float(p & 0xFFFF0000u); }

// Load 16-channel chunk CC of node n into 8 bf16-pair words.
// CC<4: x channels (coalesced along n); CC>=4: ssa (float4 x4 per node).
#define LOAD_CHUNK(CC, DST) do {                                              \
    const int c_ = (CC);                                                      \
    if (c_ < 4) {                                                             \
        const float* xr_ = x + (((size_t)b * F_ + c_ * 16) * T_ + t) * N_ + n; \
        _Pragma("unroll")                                                     \
        for (int m_ = 0; m_ < 8; ++m_) {                                      \
            float f0_ = xr_[(size_t)(2 * m_) * (T_ * N_)];                    \
            float f1_ = xr_[(size_t)(2 * m_ + 1) * (T_ * N_)];                \
            DST[m_] = packbf(f0_, f1_);                                       \
        }                                                                     \
    } else {                                                                  \
        const float* sr_ = ssa + ((size_t)bt * N_ + n) * A_ + (c_ - 4) * 16;  \
        _Pragma("unroll")                                                     \
        for (int m_ = 0; m_ < 4; ++m_) {                                      \
            float4 u_ = *(const float4*)(sr_ + 4 * m_);                       \
            DST[2 * m_]     = packbf(u_.x, u_.y);                             \
            DST[2 * m_ + 1] = packbf(u_.z, u_.w);                             \
        }                                                                     \
    }                                                                         \
} while (0)

// Pre-kernel: pack theta f32 -> bf16 pairs in MFMA B-frag order into d_ws.
// frag f = ct*4 + kk (ct = col-tile 0..7, kk = K-step/round 0..3); lane l holds
// co = ct*16 + (l&15), ci = kk*32 + (l>>4)*8 + 2*kq (+1), kq = 0..3.
__global__ __launch_bounds__(256)
void theta_pack(const float* __restrict__ theta, unsigned* __restrict__ ws) {
    int w = blockIdx.x * 256 + threadIdx.x;     // 0..8191
    int f = w >> 8, rem = w & 255;
    int l = rem >> 2, kq = rem & 3;
    int kk = f & 3, ct = f >> 2;
    int co = ct * 16 + (l & 15);
    int ci = kk * 32 + (l >> 4) * 8 + kq * 2;
    const float2 tv = *(const float2*)(theta + (size_t)co * CIN + ci);
    ws[w] = packbf(tv.x, tv.y);
}

// 1024 threads, 8 waves/EU -> 2 blocks/CU (32 waves/CU, thread-capped).
// Static grid 640 (the persistent-loop variant spills: R11/R12).
template<bool HAS_WS>
__global__ __launch_bounds__(THREADS, 8)
void hgconv(const float* __restrict__ x, const int* __restrict__ H,
            const float* __restrict__ ssa, const float* __restrict__ theta,
            const float* __restrict__ bias, float* __restrict__ out,
            const unsigned* __restrict__ thw)
{
    extern __shared__ float sf[];
    int* si = (int*)sf;

    const int tid = (int)threadIdx.x;
    const int bt  = (int)blockIdx.x;
    const int b   = bt / T_;
    const int t   = bt - b * T_;

    unsigned char*  s_srt8  = (unsigned char*)(si + L_SRT8);
    int*            s_ofn   = si + L_OFN;
    int*            s_ofe   = si + L_OFE;
    int*            s_dge   = si + L_DGE;
    int*            s_cue   = si + L_CUE;
    int*            s_dgn   = si + L_DGN;
    int*            s_cun   = si + L_CUN;
    unsigned short* s_esr16 = (unsigned short*)(si + L_ESR);
    unsigned*       s_eq16  = (unsigned*)(si + L_EQ);
    unsigned*       s_st16  = (unsigned*)(si + L_ST);
    int*            s_nid   = si + L_EQ;          // P0..P3 only
    int*            s_eid   = si + L_ST;          // P0..P3 only
    int*            s_hst   = si + L_HST;
    int*            s_crs   = si + L_CRS;
    int*            s_prm   = si + L_PRM;
    float*          s_xq    = sf + L_XQ;          // after P5

    const int n  = tid & (N_ - 1);   // node (staging / predicates)
    const int hf = tid >> 9;         // which 16-ch half of the 32-ch round

    // ---- P0: load incidence, zero degrees + histogram ----
    const int* Hb = H + (size_t)bt * (2 * EINC);
    #pragma unroll
    for (int k = 0; k < EINC / THREADS; ++k) {
        int i = tid + k * THREADS;
        s_nid[i] = Hb[i];
        s_eid[i] = Hb[EINC + i];
    }
    if (tid < N_)    s_dgn[tid] = 0;
    if (tid < NEDGE) s_dge[tid] = 0;
    if (tid < 64)    s_hst[tid] = 0;
    __syncthreads();

    // ---- P1: degrees ----
    #pragma unroll
    for (int k = 0; k < EINC / THREADS; ++k) {
        int i = tid + k * THREADS;
        atomicAdd(&s_dgn[s_nid[i]], 1);
        atomicAdd(&s_dge[s_eid[i]], 1);
    }
    __syncthreads();

    const bool act = s_dgn[n] > 0;
    u32x8 vv;
    if (act) LOAD_CHUNK(hf, vv);     // round-0 halves; hides under scans/sort

    // ---- P2: exclusive scans (wave0: edges, wave1: nodes) ----
    if (tid < 64) {
        const int ll = tid;
        int d0 = s_dge[2 * ll], d1 = s_dge[2 * ll + 1];
        int run = d0 + d1;
        int scan = run;
        #pragma unroll
        for (int d = 1; d < 64; d <<= 1) {
            int o = __shfl_up(scan, d);
            if (ll >= d) scan += o;
        }
        int excl = scan - run;
        s_ofe[2 * ll] = excl;
        s_ofe[2 * ll + 1] = excl + d0;
        if (ll == 63) s_ofe[NEDGE] = scan;
    } else if (tid < 128) {
        const int ll = tid & 63;
        int v, loc[8], run = 0;
        #pragma unroll
        for (int qq = 0; qq < 8; ++qq) { v = s_dgn[ll * 8 + qq]; loc[qq] = run; run += v; }
        int scan = run;
        #pragma unroll
        for (int d = 1; d < 64; d <<= 1) {
            int o = __shfl_up(scan, d);
            if (ll >= d) scan += o;
        }
        int excl = scan - run;
        #pragma unroll
        for (int qq = 0; qq < 8; ++qq) s_ofn[ll * 8 + qq] = excl + loc[qq];
        if (ll == 63) s_ofn[N_] = scan;
    }
    __syncthreads();

    // copy cursors + edge-degree histogram (desc buckets: high degree first)
    if (tid < N_)    s_cun[tid] = s_ofn[tid];
    if (tid < NEDGE) {
        s_cue[tid] = s_ofe[tid];
        int d = s_dge[tid];
        atomicAdd(&s_hst[63 - (d < 63 ? d : 63)], 1);
    }
    __syncthreads();

    // ---- P3: counting-sort scatter; wave0 also scans the degree histogram ----
    #pragma unroll
    for (int k = 0; k < EINC / THREADS; ++k) {
        int i = tid + k * THREADS;
        int nd = s_nid[i];
        int e  = s_eid[i];
        int pe = atomicAdd(&s_cue[e], 1);
        s_esr16[pe] = (unsigned short)nd;
        int pn = atomicAdd(&s_cun[nd], 1);
        s_srt8[pn] = (unsigned char)e;
    }
    if (tid < 64) {                  // exclusive scan of 64 buckets -> cursors
        int h = s_hst[tid];
        int scan = h;
        #pragma unroll
        for (int d = 1; d < 64; d <<= 1) {
            int o = __shfl_up(scan, d);
            if (tid >= d) scan += o;
        }
        s_crs[tid] = scan - h;
    }
    __syncthreads();                 // s_nid/s_eid DEAD; EQ/ST usable; crs ready

    // ---- P4+P5 fused: 4 rounds x {stage 32ch, gather->EQ, MFMA K-step} ----
    const int eg = tid >> 3;         // gather slot 0..127 (edge = s_prm[eg])
    const int ep = tid & 7;          // 4-channel group 0..7
    const int wv = tid >> 6, l = tid & 63;
    const int q  = l >> 4, lco = l & 15;
    const int rt = wv >> 1;          // row-tile 0..7
    const int cth = (wv & 1) * 4;    // col-tile base (0 or 4)
    const int ar = rt * 16 + lco;    // A-frag edge row
    const int aoff = ar * 16 + ((4 * q) ^ ((ar & 3) << 2));   // swizzled quad

    f32x4v acc[4];
    #pragma unroll
    for (int i = 0; i < 4; ++i) acc[i] = (f32x4v){0.f, 0.f, 0.f, 0.f};

    #pragma unroll
    for (int r = 0; r < 4; ++r) {
        if (act) {                   // stage this thread's 8 words (4 uint2, swizzled)
            #pragma unroll
            for (int p2 = 0; p2 < 4; ++p2) {
                int P = 4 * hf + p2;                       // pair index 0..7
                unsigned* sp = s_st16 + n * 16 + ((2 * P) ^ ((n & 7) << 1));
                *(uint2*)sp = make_uint2(vv[2 * p2], vv[2 * p2 + 1]);
            }
        }
        if (r == 0 && tid < NEDGE) { // degree-sorted permutation scatter
            int d = s_dge[tid];
            int pos = atomicAdd(&s_crs[63 - (d < 63 ? d : 63)], 1);
            s_prm[pos] = tid;
        }
        __syncthreads();             // B1: stage+perm visible; prev MFMA EQ-reads done

        if (r < 3 && act) LOAD_CHUNK(2 * r + 2 + hf, vv);  // reload under gather

        {   // gather 4 channels (words 2ep,2ep+1) for permuted edge
            int pe  = s_prm[eg];     // 8 lanes/group broadcast
            int gk0 = s_ofe[pe];
            int gd  = s_dge[pe];
            int gk1 = gk0 + gd;
            float gbinv = (gd > 0) ? 1.0f / (float)gd : 0.0f;
            float a0 = 0.f, a1 = 0.f, a2 = 0.f, a3 = 0.f;
            for (int k = gk0; k < gk1; ++k) {
                int nd = (int)s_esr16[k];
                uint2 pr = *(const uint2*)(s_st16 + nd * 16
                                + ((2 * ep) ^ ((nd & 7) << 1)));
                a0 += bflo(pr.x); a1 += bfhi(pr.x);
                a2 += bflo(pr.y); a3 += bfhi(pr.y);
            }
            unsigned* qp = s_eq16 + pe * 16 + ((2 * ep) ^ ((pe & 3) << 2));
            *(uint2*)qp = make_uint2(packbf(a0 * gbinv, a1 * gbinv),
                                     packbf(a2 * gbinv, a3 * gbinv));
        }
        __syncthreads();             // B2: EQ visible; ST reads done

        {   // MFMA K-step r: A = EQ row-tile, B = theta frags
            bf16x8v av = *(const bf16x8v*)(s_eq16 + aoff);
            if (HAS_WS) {
                #pragma unroll
                for (int i = 0; i < 4; ++i) {
                    uint4 u = ((const uint4*)thw)[((cth + i) * 4 + r) * 64 + l];
                    acc[i] = __builtin_amdgcn_mfma_f32_16x16x32_bf16(
                        av, *(const bf16x8v*)&u, acc[i], 0, 0, 0);
                }
            } else {
                #pragma unroll
                for (int i = 0; i < 4; ++i) {
                    const float* tp = theta + (size_t)((cth + i) * 16 + lco) * CIN
                                    + r * 32 + q * 8;
                    float4 t0 = *(const float4*)tp;
                    float4 t1 = *(const float4*)(tp + 4);
                    unsigned pw[4] = { packbf(t0.x, t0.y), packbf(t0.z, t0.w),
                                       packbf(t1.x, t1.y), packbf(t1.z, t1.w) };
                    acc[i] = __builtin_amdgcn_mfma_f32_16x16x32_bf16(
                        av, *(const bf16x8v*)pw, acc[i], 0, 0, 0);
                }
            }
        }
    }
    __syncthreads();                 // B3: all EQ reads done; Xq overlay may begin

    // ---- Xq write: D-frag (col = lco, row = q*4+reg) -> f32 [128][132] ----
    #pragma unroll
    for (int i = 0; i < 4; ++i) {
        const int co = (cth + i) * 16 + lco;
        #pragma unroll
        for (int reg = 0; reg < 4; ++reg)
            s_xq[(rt * 16 + q * 4 + reg) * XQS + co] = acc[i][reg];
    }
    __syncthreads();

    // ---- P6: single pass; per visit one b128; float4 coalesced store ----
    {
        const int lw = tid & 31;
        const int g  = tid >> 5;     // 0..31
        float4 bsv = *(const float4*)(bias + 4 * lw);
        for (int nn = g; nn < N_; nn += 32) {
            int o0 = s_ofn[nn], o1 = s_ofn[nn + 1];
            float f0 = 0.f, f1 = 0.f, f2 = 0.f, f3 = 0.f;
            for (int k = o0; k < o1; ++k) {
                int e = (int)s_srt8[k];
                float4 v = *(const float4*)(s_xq + e * XQS + 4 * lw);
                f0 += v.x; f1 += v.y; f2 += v.z; f3 += v.w;
            }
            float dinv = (o1 > o0) ? 1.0f / (float)(o1 - o0) : 0.0f;
            float* op = out + ((size_t)bt * N_ + nn) * COUT + 4 * lw;
            *(float4*)op = make_float4(f0 * dinv + bsv.x, f1 * dinv + bsv.y,
                                       f2 * dinv + bsv.z, f3 * dinv + bsv.w);
        }
    }
}

} // namespace

extern "C" void kernel_launch(void* const* d_in, const int* in_sizes, int n_in,
                              void* d_out, int out_size, void* d_ws, size_t ws_size,
                              hipStream_t stream) {
    const float* x     = (const float*)d_in[0];
    const int*   H     = (const int*)d_in[1];
    const float* ssa   = (const float*)d_in[2];
    // d_in[3] = W, unused by the conv (matches reference)
    const float* theta = (const float*)d_in[4];
    const float* bias  = (const float*)d_in[5];
    float* outp = (float*)d_out;

    const bool use_ws = (d_ws != nullptr) && (ws_size >= 32768);
    if (use_ws) {
        hipLaunchKernelGGL(theta_pack, dim3(32), dim3(256), 0, stream,
                           theta, (unsigned*)d_ws);
        (void)hipFuncSetAttribute((const void*)&hgconv<true>,
                                  hipFuncAttributeMaxDynamicSharedMemorySize, LDS_BYTES);
        hipLaunchKernelGGL(hgconv<true>, dim3(NBT), dim3(THREADS), LDS_BYTES,
                           stream, x, H, ssa, theta, bias, outp,
                           (const unsigned*)d_ws);
    } else {
        (void)hipFuncSetAttribute((const void*)&hgconv<false>,
                                  hipFuncAttributeMaxDynamicSharedMemorySize, LDS_BYTES);
        hipLaunchKernelGGL(hgconv<false>, dim3(NBT), dim3(THREADS), LDS_BYTES,
                           stream, x, H, ssa, theta, bias, outp, nullptr);
    }
}